// Round 1
// baseline (2087.250 us; speedup 1.0000x reference)
//
#include <hip/hip_runtime.h>
#include <hip/hip_bf16.h>

#define N_ENT   100000
#define N_RELT  474        // 2*237
#define DIM     128
#define N_EDGE  500000
#define BATCH_Q 4096

// ---- output layout (float offsets) ----
#define OUT_SUBR 0
#define OUT_SUBI (BATCH_Q * DIM)          // 524288
#define OUT_RELR (2 * BATCH_Q * DIM)      // 1048576
#define OUT_RELI (3 * BATCH_Q * DIM)      // 1572864
#define OUT_ER   (4 * BATCH_Q * DIM)      // 2097152
#define OUT_EI   (OUT_ER + N_ENT * DIM)   // 14897152

// ---- workspace layout (float offsets) ----
#define WS_ENTI  0
#define WS_RELI  (N_ENT * DIM)                 // 12800000
#define WS_RELOR (WS_RELI + N_RELT * DIM)      // 12860672
#define WS_RELOI (WS_RELOR + N_RELT * DIM)     // 12921344
#define WS_DENOM (WS_RELOI + N_RELT * DIM)     // 12982016
#define WS_BF16  (WS_DENOM + N_ENT)            // 13082016 (cast to bf16*)

// Convert the three matrices used by hot kernels to bf16 (halves L2 traffic;
// rel error 0.4% -> abs error ~6e-6 on outputs, threshold is 2.7e-3).
__global__ void convert_w(const float* __restrict__ P,
                          const float* __restrict__ Wr,
                          const float* __restrict__ Wi,
                          __hip_bfloat16* __restrict__ dst) {
    int i = blockIdx.x * 256 + threadIdx.x;   // 49152 total
    if (i < 16384)        dst[i] = __float2bfloat16(P[i]);
    else if (i < 32768)   dst[i] = __float2bfloat16(Wr[i - 16384]);
    else if (i < 49152)   dst[i] = __float2bfloat16(Wi[i - 32768]);
}

// ent_i = init_embed_imag @ im_proj   [100000,128] @ [128,128]
__launch_bounds__(512, 4)
__global__ void proj_ent(const float* __restrict__ imag,
                         const __hip_bfloat16* __restrict__ Pb,
                         float* __restrict__ ent_i) {
    __shared__ __align__(16) float sx[64 * 128];   // 32 KB
    const int t = threadIdx.x;
    const int base = blockIdx.x * 64;
    for (int i = t; i < 64 * 128; i += 512) {
        int r = i >> 7, k = i & 127;
        int gr = base + r;
        sx[i] = (gr < N_ENT) ? imag[(size_t)gr * DIM + k] : 0.f;
    }
    __syncthreads();
    const int lane = t & 63, g = t >> 6;
    const int j0 = lane, j1 = lane + 64;
    float y0[8], y1[8];
#pragma unroll
    for (int e = 0; e < 8; ++e) { y0[e] = 0.f; y1[e] = 0.f; }
    for (int k = 0; k < 128; k += 4) {
        float p0[4], p1[4];
#pragma unroll
        for (int q = 0; q < 4; ++q) {
            p0[q] = __bfloat162float(Pb[(k + q) * 128 + j0]);
            p1[q] = __bfloat162float(Pb[(k + q) * 128 + j1]);
        }
#pragma unroll
        for (int e = 0; e < 8; ++e) {
            const float4 xv = *reinterpret_cast<const float4*>(&sx[(g * 8 + e) * 128 + k]);
            y0[e] = fmaf(xv.x, p0[0], y0[e]); y0[e] = fmaf(xv.y, p0[1], y0[e]);
            y0[e] = fmaf(xv.z, p0[2], y0[e]); y0[e] = fmaf(xv.w, p0[3], y0[e]);
            y1[e] = fmaf(xv.x, p1[0], y1[e]); y1[e] = fmaf(xv.y, p1[1], y1[e]);
            y1[e] = fmaf(xv.z, p1[2], y1[e]); y1[e] = fmaf(xv.w, p1[3], y1[e]);
        }
    }
#pragma unroll
    for (int e = 0; e < 8; ++e) {
        int gr = base + g * 8 + e;
        if (gr < N_ENT) {
            ent_i[(size_t)gr * DIM + j0] = y0[e];
            ent_i[(size_t)gr * DIM + j1] = y1[e];
        }
    }
}

// Relation path: rel_i = imag @ P ; rel_out_i = tanh(rel_i @ Wrel) ;
// rel_out_r = tanh(real @ Wrel). Row-local chain -> one block per row.
__global__ void rel_kernel(const float* __restrict__ rel_real,
                           const float* __restrict__ rel_imag,
                           const float* __restrict__ P,
                           const float* __restrict__ Wrel,
                           float* __restrict__ rel_i,
                           float* __restrict__ rel_or,
                           float* __restrict__ rel_oi) {
    __shared__ float s_im[128], s_re[128], s_ri[128];
    const int j = threadIdx.x;
    const int r = blockIdx.x;
    s_im[j] = rel_imag[r * 128 + j];
    s_re[j] = rel_real[r * 128 + j];
    __syncthreads();
    float acc = 0.f;
    for (int k = 0; k < 128; ++k) acc = fmaf(s_im[k], P[k * 128 + j], acc);
    rel_i[r * 128 + j] = acc;
    s_ri[j] = acc;
    __syncthreads();
    float ai = 0.f, ar = 0.f;
    for (int k = 0; k < 128; ++k) {
        float w = Wrel[k * 128 + j];
        ai = fmaf(s_ri[k], w, ai);
        ar = fmaf(s_re[k], w, ar);
    }
    rel_oi[r * 128 + j] = tanhf(ai);
    rel_or[r * 128 + j] = tanhf(ar);
}

// The hot kernel: 64 edges per block. gather -> complex compose (LDS) ->
// h = m @ W (bf16 W streamed from L2, m broadcast from LDS) -> logit
// (wave butterfly reduce) -> ex = exp(leaky) -> atomic scatter of
// denom and ex*h into the output accumulator region.
__launch_bounds__(512, 4)
__global__ void edge_kernel(const int* __restrict__ eidx,
                            const int* __restrict__ etype,
                            const float* __restrict__ ent_r,
                            const float* __restrict__ ent_i,
                            const float* __restrict__ rel_r,
                            const float* __restrict__ rel_i,
                            const __hip_bfloat16* __restrict__ Wrb,
                            const __hip_bfloat16* __restrict__ Wib,
                            const float* __restrict__ att_a,
                            float* __restrict__ num_r,
                            float* __restrict__ num_i,
                            float* __restrict__ denom) {
    __shared__ __align__(16) float m_r[64 * 128];   // 32 KB
    __shared__ __align__(16) float m_i[64 * 128];   // 32 KB
    __shared__ int s_src[64], s_et[64], s_dst[64];
    const int t = threadIdx.x;
    const int base = blockIdx.x * 64;

    if (t < 64) {
        int ge = base + t;
        bool ok = ge < N_EDGE;
        s_src[t] = ok ? eidx[ge] : 0;
        s_et[t]  = ok ? etype[ge] : 0;
        s_dst[t] = ok ? eidx[N_EDGE + ge] : 0;
    }
    __syncthreads();

    // stage m_r, m_i for 64 edges (coalesced 256B gathers per wave)
    for (int i = t; i < 64 * 128; i += 512) {
        int e = i >> 7, k = i & 127;
        bool ok = (base + e) < N_EDGE;
        int src = s_src[e], et = s_et[e];
        float er = ent_r[(size_t)src * DIM + k];
        float ei = ent_i[(size_t)src * DIM + k];
        float rr = rel_r[et * DIM + k];
        float ri = rel_i[et * DIM + k];
        m_r[i] = ok ? (er * rr - ei * ri) : 0.f;
        m_i[i] = ok ? (er * ri + ei * rr) : 0.f;
    }
    __syncthreads();

    const int lane = t & 63, g = t >> 6;     // 8 wave-groups, 8 edges each
    const int j0 = lane, j1 = lane + 64;
    const float a_r0 = att_a[j0], a_i0 = att_a[128 + j0];
    const float a_r1 = att_a[j1], a_i1 = att_a[128 + j1];

    float hr0[8], hr1[8], hi0[8], hi1[8];
#pragma unroll
    for (int e = 0; e < 8; ++e) { hr0[e] = 0.f; hr1[e] = 0.f; hi0[e] = 0.f; hi1[e] = 0.f; }

    for (int k = 0; k < 128; k += 4) {
        float wr0[4], wr1[4], wi0[4], wi1[4];
#pragma unroll
        for (int q = 0; q < 4; ++q) {
            wr0[q] = __bfloat162float(Wrb[(k + q) * 128 + j0]);
            wr1[q] = __bfloat162float(Wrb[(k + q) * 128 + j1]);
            wi0[q] = __bfloat162float(Wib[(k + q) * 128 + j0]);
            wi1[q] = __bfloat162float(Wib[(k + q) * 128 + j1]);
        }
#pragma unroll
        for (int e = 0; e < 8; ++e) {
            const float4 ar = *reinterpret_cast<const float4*>(&m_r[(g * 8 + e) * 128 + k]);
            const float4 ai = *reinterpret_cast<const float4*>(&m_i[(g * 8 + e) * 128 + k]);
            hr0[e] = fmaf(ar.x, wr0[0], hr0[e]); hr0[e] = fmaf(ar.y, wr0[1], hr0[e]);
            hr0[e] = fmaf(ar.z, wr0[2], hr0[e]); hr0[e] = fmaf(ar.w, wr0[3], hr0[e]);
            hr1[e] = fmaf(ar.x, wr1[0], hr1[e]); hr1[e] = fmaf(ar.y, wr1[1], hr1[e]);
            hr1[e] = fmaf(ar.z, wr1[2], hr1[e]); hr1[e] = fmaf(ar.w, wr1[3], hr1[e]);
            hi0[e] = fmaf(ai.x, wi0[0], hi0[e]); hi0[e] = fmaf(ai.y, wi0[1], hi0[e]);
            hi0[e] = fmaf(ai.z, wi0[2], hi0[e]); hi0[e] = fmaf(ai.w, wi0[3], hi0[e]);
            hi1[e] = fmaf(ai.x, wi1[0], hi1[e]); hi1[e] = fmaf(ai.y, wi1[1], hi1[e]);
            hi1[e] = fmaf(ai.z, wi1[2], hi1[e]); hi1[e] = fmaf(ai.w, wi1[3], hi1[e]);
        }
    }

    // logit partial per lane, butterfly-reduce over the 64-lane wave
    float p[8];
#pragma unroll
    for (int e = 0; e < 8; ++e)
        p[e] = hr0[e] * a_r0 + hi0[e] * a_i0 + hr1[e] * a_r1 + hi1[e] * a_i1;
#pragma unroll
    for (int off = 1; off < 64; off <<= 1) {
#pragma unroll
        for (int e = 0; e < 8; ++e) p[e] += __shfl_xor(p[e], off, 64);
    }

    // softmax is shift-invariant; logits are ~1e-3 so exp without max is safe
    float ex[8];
#pragma unroll
    for (int e = 0; e < 8; ++e) {
        float l = p[e];
        l = l > 0.f ? l : 0.2f * l;     // leaky_relu(0.2)
        ex[e] = expf(l);
    }
    if (lane == 0) {
#pragma unroll
        for (int e = 0; e < 8; ++e) {
            if (base + g * 8 + e < N_EDGE) atomicAdd(&denom[s_dst[g * 8 + e]], ex[e]);
        }
    }

    // scatter numerator: coalesced 256B atomic runs per edge
#pragma unroll
    for (int e = 0; e < 8; ++e) {
        int ge = base + g * 8 + e;
        if (ge < N_EDGE) {
            int d = s_dst[g * 8 + e];
            float w = ex[e];
            float* br = num_r + (size_t)d * DIM;
            float* bi = num_i + (size_t)d * DIM;
            atomicAdd(&br[j0], w * hr0[e]);
            atomicAdd(&br[j1], w * hr1[e]);
            atomicAdd(&bi[j0], w * hi0[e]);
            atomicAdd(&bi[j1], w * hi1[e]);
        }
    }
}

// out = tanh(num / (denom + 1e-10)) in place over e_r and e_i regions
__global__ void finalize_kernel(float* __restrict__ out,
                                const float* __restrict__ denom) {
    int idx = blockIdx.x * 256 + threadIdx.x;       // float4 index
    if (idx >= (2 * N_ENT * DIM) / 4) return;       // 6,400,000
    int rowid = idx >> 5;                            // 32 float4 per row
    int v = (rowid < N_ENT) ? rowid : rowid - N_ENT;
    float inv = 1.0f / (denom[v] + 1e-10f);
    float4* p = reinterpret_cast<float4*>(out + OUT_ER) + idx;
    float4 x = *p;
    x.x = tanhf(x.x * inv);
    x.y = tanhf(x.y * inv);
    x.z = tanhf(x.z * inv);
    x.w = tanhf(x.w * inv);
    *p = x;
}

// sub_r/sub_i gathered from finalized e_r/e_i; rel_r/rel_i from ws tables
__global__ void gather_kernel(const int* __restrict__ sub,
                              const int* __restrict__ rel,
                              const float* __restrict__ relor,
                              const float* __restrict__ reloi,
                              float* __restrict__ out) {
    int idx = blockIdx.x * 256 + threadIdx.x;   // float4 index, 524288 total
    if (idx >= 4 * BATCH_Q * 32) return;
    int arr = idx >> 17;         // 131072 float4 per array
    int rem = idx & 131071;
    int b = rem >> 5, c = rem & 31;
    const float* srcp;
    float* dstp;
    if (arr == 0)      { srcp = out + OUT_ER + (size_t)sub[b] * DIM; dstp = out + OUT_SUBR; }
    else if (arr == 1) { srcp = out + OUT_EI + (size_t)sub[b] * DIM; dstp = out + OUT_SUBI; }
    else if (arr == 2) { srcp = relor + (size_t)rel[b] * DIM;        dstp = out + OUT_RELR; }
    else               { srcp = reloi + (size_t)rel[b] * DIM;        dstp = out + OUT_RELI; }
    reinterpret_cast<float4*>(dstp + (size_t)b * DIM)[c] =
        reinterpret_cast<const float4*>(srcp)[c];
}

extern "C" void kernel_launch(void* const* d_in, const int* in_sizes, int n_in,
                              void* d_out, int out_size, void* d_ws, size_t ws_size,
                              hipStream_t stream) {
    const int*   eidx    = (const int*)d_in[0];
    const int*   etype   = (const int*)d_in[1];
    const int*   sub     = (const int*)d_in[2];
    const int*   rel     = (const int*)d_in[3];
    const float* emb_r   = (const float*)d_in[4];
    const float* emb_i   = (const float*)d_in[5];
    const float* relreal = (const float*)d_in[6];
    const float* relimag = (const float*)d_in[7];
    const float* im_proj = (const float*)d_in[8];
    const float* w_real  = (const float*)d_in[9];
    const float* w_imag  = (const float*)d_in[10];
    const float* w_rel   = (const float*)d_in[11];
    const float* att_a   = (const float*)d_in[12];

    float* out = (float*)d_out;
    float* ws  = (float*)d_ws;

    float* ent_i  = ws + WS_ENTI;
    float* rel_i  = ws + WS_RELI;
    float* relor  = ws + WS_RELOR;
    float* reloi  = ws + WS_RELOI;
    float* denom  = ws + WS_DENOM;
    __hip_bfloat16* wb  = reinterpret_cast<__hip_bfloat16*>(ws + WS_BF16);
    __hip_bfloat16* Pb  = wb;
    __hip_bfloat16* Wrb = wb + 16384;
    __hip_bfloat16* Wib = wb + 32768;

    // zero the accumulator region of d_out (poisoned 0xAA) and denom
    hipMemsetAsync(out + OUT_ER, 0, (size_t)(2 * N_ENT * DIM) * sizeof(float), stream);
    hipMemsetAsync(denom, 0, (size_t)N_ENT * sizeof(float), stream);

    convert_w<<<192, 256, 0, stream>>>(im_proj, w_real, w_imag, wb);
    proj_ent<<<1563, 512, 0, stream>>>(emb_i, Pb, ent_i);
    rel_kernel<<<474, 128, 0, stream>>>(relreal, relimag, im_proj, w_rel,
                                        rel_i, relor, reloi);
    edge_kernel<<<7813, 512, 0, stream>>>(eidx, etype, emb_r, ent_i,
                                          relreal, rel_i, Wrb, Wib, att_a,
                                          out + OUT_ER, out + OUT_EI, denom);
    finalize_kernel<<<25000, 256, 0, stream>>>(out, denom);
    gather_kernel<<<2048, 256, 0, stream>>>(sub, rel, relor, reloi, out);
}

// Round 2
// 1318.851 us; speedup vs baseline: 1.5826x; 1.5826x over previous
//
#include <hip/hip_runtime.h>
#include <hip/hip_bf16.h>

#define N_ENT   100000
#define N_RELT  474        // 2*237
#define DIM     128
#define N_EDGE  500000
#define BATCH_Q 4096

typedef __attribute__((ext_vector_type(8))) short short8v;   // 8 bf16 (4 VGPRs)
typedef __attribute__((ext_vector_type(4))) float f32x4;

// ---- output layout (float offsets) ----
#define OUT_SUBR 0
#define OUT_SUBI (BATCH_Q * DIM)          // 524288
#define OUT_RELR (2 * BATCH_Q * DIM)      // 1048576
#define OUT_RELI (3 * BATCH_Q * DIM)      // 1572864
#define OUT_ER   (4 * BATCH_Q * DIM)      // 2097152
#define OUT_EI   (OUT_ER + N_ENT * DIM)   // 14897152
// d_out[0 .. 2097152) is scratch until gather_kernel (the final kernel)
// writes it: sorted packed src|et (500K int), sorted dst (500K int),
// cnt/cursor (100K int).

// ---- workspace layout (float offsets) ----
#define WS_ENTI  0
#define WS_RELI  (N_ENT * DIM)                 // 12800000
#define WS_RELOR (WS_RELI + N_RELT * DIM)
#define WS_RELOI (WS_RELOR + N_RELT * DIM)
#define WS_DENOM (WS_RELOI + N_RELT * DIM)
#define WS_BF16  (WS_DENOM + N_ENT)            // bf16: Pb(16384) Wtr(16384) Wti(16384)

__device__ __forceinline__ unsigned int pack2bf(float a, float b) {
    // truncation to bf16 (avg rel err 0.4%, fine vs 2.7e-3 threshold)
    return (__float_as_uint(a) >> 16) | (__float_as_uint(b) & 0xFFFF0000u);
}

// Pb = bf16(im_proj) [k][j]; Wtr/Wti = bf16 TRANSPOSED: Wt[n][k] = W[k][n]
__global__ void convert_w(const float* __restrict__ P,
                          const float* __restrict__ Wr,
                          const float* __restrict__ Wi,
                          __hip_bfloat16* __restrict__ dst) {
    int i = blockIdx.x * 256 + threadIdx.x;   // 49152 total
    if (i < 16384) {
        dst[i] = __float2bfloat16(P[i]);
    } else if (i < 32768) {
        int j = i - 16384; int n = j >> 7, k = j & 127;
        dst[i] = __float2bfloat16(Wr[k * 128 + n]);
    } else if (i < 49152) {
        int j = i - 32768; int n = j >> 7, k = j & 127;
        dst[i] = __float2bfloat16(Wi[k * 128 + n]);
    }
}

// ---------------- counting sort by destination ----------------
__global__ void hist_kernel(const int* __restrict__ eidx, int* __restrict__ cnt) {
    int e = blockIdx.x * 256 + threadIdx.x;
    if (e < N_EDGE) atomicAdd(&cnt[eidx[N_EDGE + e]], 1);
}

// single-block exclusive scan of cnt[100000], in place (cnt becomes cursor)
__global__ void scan_kernel(int* __restrict__ cnt) {
    __shared__ int ssum[1024];
    const int t = threadIdx.x;
    const int C = (N_ENT + 1023) / 1024;    // 98
    int beg = t * C, end = beg + C; if (end > N_ENT) end = N_ENT;
    int s = 0;
    for (int i = beg; i < end; ++i) s += cnt[i];
    ssum[t] = s;
    __syncthreads();
    for (int off = 1; off < 1024; off <<= 1) {
        int v = (t >= off) ? ssum[t - off] : 0;
        __syncthreads();
        ssum[t] += v;
        __syncthreads();
    }
    int base = t ? ssum[t - 1] : 0;
    for (int i = beg; i < end; ++i) { int c = cnt[i]; cnt[i] = base; base += c; }
}

__global__ void scatter_kernel(const int* __restrict__ eidx,
                               const int* __restrict__ etype,
                               int* __restrict__ cursor,
                               int* __restrict__ sp,   // src | et<<17
                               int* __restrict__ sd) { // dst (nondecreasing)
    int e = blockIdx.x * 256 + threadIdx.x;
    if (e >= N_EDGE) return;
    int d = eidx[N_EDGE + e];
    int p = atomicAdd(&cursor[d], 1);
    sp[p] = eidx[e] | (etype[e] << 17);
    sd[p] = d;
}

// ent_i = init_embed_imag @ im_proj   [100000,128] @ [128,128]
__launch_bounds__(512, 4)
__global__ void proj_ent(const float* __restrict__ imag,
                         const __hip_bfloat16* __restrict__ Pb,
                         float* __restrict__ ent_i) {
    __shared__ __align__(16) float sx[64 * 128];
    const int t = threadIdx.x;
    const int base = blockIdx.x * 64;
    for (int i = t; i < 64 * 128; i += 512) {
        int r = i >> 7, k = i & 127;
        int gr = base + r;
        sx[i] = (gr < N_ENT) ? imag[(size_t)gr * DIM + k] : 0.f;
    }
    __syncthreads();
    const int lane = t & 63, g = t >> 6;
    const int j0 = lane, j1 = lane + 64;
    float y0[8], y1[8];
#pragma unroll
    for (int e = 0; e < 8; ++e) { y0[e] = 0.f; y1[e] = 0.f; }
    for (int k = 0; k < 128; k += 4) {
        float p0[4], p1[4];
#pragma unroll
        for (int q = 0; q < 4; ++q) {
            p0[q] = __bfloat162float(Pb[(k + q) * 128 + j0]);
            p1[q] = __bfloat162float(Pb[(k + q) * 128 + j1]);
        }
#pragma unroll
        for (int e = 0; e < 8; ++e) {
            const float4 xv = *reinterpret_cast<const float4*>(&sx[(g * 8 + e) * 128 + k]);
            y0[e] = fmaf(xv.x, p0[0], y0[e]); y0[e] = fmaf(xv.y, p0[1], y0[e]);
            y0[e] = fmaf(xv.z, p0[2], y0[e]); y0[e] = fmaf(xv.w, p0[3], y0[e]);
            y1[e] = fmaf(xv.x, p1[0], y1[e]); y1[e] = fmaf(xv.y, p1[1], y1[e]);
            y1[e] = fmaf(xv.z, p1[2], y1[e]); y1[e] = fmaf(xv.w, p1[3], y1[e]);
        }
    }
#pragma unroll
    for (int e = 0; e < 8; ++e) {
        int gr = base + g * 8 + e;
        if (gr < N_ENT) {
            ent_i[(size_t)gr * DIM + j0] = y0[e];
            ent_i[(size_t)gr * DIM + j1] = y1[e];
        }
    }
}

__global__ void rel_kernel(const float* __restrict__ rel_real,
                           const float* __restrict__ rel_imag,
                           const float* __restrict__ P,
                           const float* __restrict__ Wrel,
                           float* __restrict__ rel_i,
                           float* __restrict__ rel_or,
                           float* __restrict__ rel_oi) {
    __shared__ float s_im[128], s_re[128], s_ri[128];
    const int j = threadIdx.x;
    const int r = blockIdx.x;
    s_im[j] = rel_imag[r * 128 + j];
    s_re[j] = rel_real[r * 128 + j];
    __syncthreads();
    float acc = 0.f;
    for (int k = 0; k < 128; ++k) acc = fmaf(s_im[k], P[k * 128 + j], acc);
    rel_i[r * 128 + j] = acc;
    s_ri[j] = acc;
    __syncthreads();
    float ai = 0.f, ar = 0.f;
    for (int k = 0; k < 128; ++k) {
        float w = Wrel[k * 128 + j];
        ai = fmaf(s_ri[k], w, ai);
        ar = fmaf(s_re[k], w, ar);
    }
    rel_oi[r * 128 + j] = tanhf(ai);
    rel_or[r * 128 + j] = tanhf(ar);
}

// ---------------- MFMA edge kernel (64 sorted edges / block) ----------------
// m (bf16, XOR-swizzled chunks) in LDS; h = m @ W via mfma_f32_16x16x32_bf16.
// Wave g: mtile = g&3 (16 edges), ntile = g>>2 (64 cols). Per GEMM (r and i):
// 4 nf-frags x 4 K-steps = 16 MFMA.
// A-frag: lane holds m[mtile*16+(l&15)][ks*32+(l>>4)*8 + 0..7]
// B-frag: lane holds W[ks*32+(l>>4)*8 + 0..7][ntile*64+nf*16+(l&15)]  (= Wt rows)
// C/D (verified): reg j of lane l -> row (l>>4)*4+j (edge), col l&15.
__launch_bounds__(512, 6)
__global__ void edge_kernel(const int* __restrict__ sp,
                            const int* __restrict__ sd,
                            const float* __restrict__ ent_r,
                            const float* __restrict__ ent_i,
                            const float* __restrict__ rel_r,
                            const float* __restrict__ rel_i,
                            const unsigned short* __restrict__ Wtr,
                            const unsigned short* __restrict__ Wti,
                            const float* __restrict__ att_a,
                            float* __restrict__ num_r,
                            float* __restrict__ num_i,
                            float* __restrict__ denom) {
    __shared__ __align__(16) unsigned short m_r_sh[64 * 128];  // 16 KB
    __shared__ __align__(16) unsigned short m_i_sh[64 * 128];  // 16 KB
    __shared__ float plog[64][2];
    __shared__ int s_se[64], s_dst[64];
    const int t = threadIdx.x;
    const int base = blockIdx.x * 64;

    if (t < 64) {
        int ge = base + t;
        bool ok = ge < N_EDGE;
        s_se[t]  = ok ? sp[ge] : 0;
        s_dst[t] = ok ? sd[ge] : 0;
    }
    __syncthreads();

    // stage m as bf16, chunk-swizzled: logical chunk c (k=8c..8c+7) of row e
    // stored at chunk (c ^ (e&15)). 1024 chunks / 512 threads = 2 iters.
    for (int it = 0; it < 2; ++it) {
        int i = t + it * 512;
        int e = i >> 4, c = i & 15;
        bool ok = (base + e) < N_EDGE;
        int pk = s_se[e];
        int src = pk & 0x1FFFF, et = pk >> 17;
        const float* pr = ent_r + (size_t)src * DIM + c * 8;
        const float* pi = ent_i + (size_t)src * DIM + c * 8;
        const float* qr = rel_r + (size_t)et * DIM + c * 8;
        const float* qi = rel_i + (size_t)et * DIM + c * 8;
        float4 er0 = reinterpret_cast<const float4*>(pr)[0];
        float4 er1 = reinterpret_cast<const float4*>(pr)[1];
        float4 ei0 = reinterpret_cast<const float4*>(pi)[0];
        float4 ei1 = reinterpret_cast<const float4*>(pi)[1];
        float4 rr0 = reinterpret_cast<const float4*>(qr)[0];
        float4 rr1 = reinterpret_cast<const float4*>(qr)[1];
        float4 ri0 = reinterpret_cast<const float4*>(qi)[0];
        float4 ri1 = reinterpret_cast<const float4*>(qi)[1];
        float r[8], im[8];
        r[0] = er0.x*rr0.x - ei0.x*ri0.x;  im[0] = er0.x*ri0.x + ei0.x*rr0.x;
        r[1] = er0.y*rr0.y - ei0.y*ri0.y;  im[1] = er0.y*ri0.y + ei0.y*rr0.y;
        r[2] = er0.z*rr0.z - ei0.z*ri0.z;  im[2] = er0.z*ri0.z + ei0.z*rr0.z;
        r[3] = er0.w*rr0.w - ei0.w*ri0.w;  im[3] = er0.w*ri0.w + ei0.w*rr0.w;
        r[4] = er1.x*rr1.x - ei1.x*ri1.x;  im[4] = er1.x*ri1.x + ei1.x*rr1.x;
        r[5] = er1.y*rr1.y - ei1.y*ri1.y;  im[5] = er1.y*ri1.y + ei1.y*rr1.y;
        r[6] = er1.z*rr1.z - ei1.z*ri1.z;  im[6] = er1.z*ri1.z + ei1.z*rr1.z;
        r[7] = er1.w*rr1.w - ei1.w*ri1.w;  im[7] = er1.w*ri1.w + ei1.w*rr1.w;
        uint4 ur, ui;
        if (ok) {
            ur.x = pack2bf(r[0], r[1]); ur.y = pack2bf(r[2], r[3]);
            ur.z = pack2bf(r[4], r[5]); ur.w = pack2bf(r[6], r[7]);
            ui.x = pack2bf(im[0], im[1]); ui.y = pack2bf(im[2], im[3]);
            ui.z = pack2bf(im[4], im[5]); ui.w = pack2bf(im[6], im[7]);
        } else {
            ur.x = ur.y = ur.z = ur.w = 0u;
            ui.x = ui.y = ui.z = ui.w = 0u;
        }
        int idx = e * 128 + ((c ^ (e & 15)) << 3);   // ushort index, 16B aligned
        *reinterpret_cast<uint4*>(&m_r_sh[idx]) = ur;
        *reinterpret_cast<uint4*>(&m_i_sh[idx]) = ui;
    }
    __syncthreads();

    const int lane = t & 63, g = t >> 6;
    const int mtile = g & 3, ntile = g >> 2;
    const int l15 = lane & 15, l4 = lane >> 4;
    const int arow = mtile * 16 + l15;

    f32x4 accr[4], acci[4];
#pragma unroll
    for (int nf = 0; nf < 4; ++nf) {
        accr[nf] = (f32x4){0.f, 0.f, 0.f, 0.f};
        acci[nf] = (f32x4){0.f, 0.f, 0.f, 0.f};
    }
#pragma unroll
    for (int ks = 0; ks < 4; ++ks) {
        int chunkx = (ks * 4 + l4) ^ l15;
        int aidx = arow * 128 + chunkx * 8;
        short8v a_r = *reinterpret_cast<const short8v*>(&m_r_sh[aidx]);
        short8v a_i = *reinterpret_cast<const short8v*>(&m_i_sh[aidx]);
        int kb = ks * 32 + l4 * 8;
#pragma unroll
        for (int nf = 0; nf < 4; ++nf) {
            int n = ntile * 64 + nf * 16 + l15;
            short8v b_r = *reinterpret_cast<const short8v*>(&Wtr[n * 128 + kb]);
            short8v b_i = *reinterpret_cast<const short8v*>(&Wti[n * 128 + kb]);
            accr[nf] = __builtin_amdgcn_mfma_f32_16x16x32_bf16(a_r, b_r, accr[nf], 0, 0, 0);
            acci[nf] = __builtin_amdgcn_mfma_f32_16x16x32_bf16(a_i, b_i, acci[nf], 0, 0, 0);
        }
    }

    // partial logits: this wave's 64 cols for its 16 edges
    float pj[4] = {0.f, 0.f, 0.f, 0.f};
#pragma unroll
    for (int nf = 0; nf < 4; ++nf) {
        int n = ntile * 64 + nf * 16 + l15;
        float ar = att_a[n], ai = att_a[128 + n];
#pragma unroll
        for (int j = 0; j < 4; ++j)
            pj[j] += accr[nf][j] * ar + acci[nf][j] * ai;
    }
#pragma unroll
    for (int off = 1; off < 16; off <<= 1) {
#pragma unroll
        for (int j = 0; j < 4; ++j) pj[j] += __shfl_xor(pj[j], off, 64);
    }
    if (l15 == 0) {
#pragma unroll
        for (int j = 0; j < 4; ++j)
            plog[mtile * 16 + l4 * 4 + j][ntile] = pj[j];
    }
    __syncthreads();

    float exv[4];
#pragma unroll
    for (int j = 0; j < 4; ++j) {
        int eg = mtile * 16 + l4 * 4 + j;
        float lg = plog[eg][0] + plog[eg][1];
        lg = lg > 0.f ? lg : 0.2f * lg;       // leaky_relu(0.2)
        exv[j] = expf(lg);                    // logits ~1e-3: max-shift not needed
    }
    if (ntile == 0 && l15 == 0) {
#pragma unroll
        for (int j = 0; j < 4; ++j) {
            int eg = mtile * 16 + l4 * 4 + j;
            if (base + eg < N_EDGE) atomicAdd(&denom[s_dst[eg]], exv[j]);
        }
    }

    // scatter ex*h — sorted dst => contiguous 64B runs with L2 locality
#pragma unroll
    for (int j = 0; j < 4; ++j) {
        int eg = mtile * 16 + l4 * 4 + j;
        if (base + eg < N_EDGE) {
            int d = s_dst[eg];
            float w = exv[j];
#pragma unroll
            for (int nf = 0; nf < 4; ++nf) {
                int col = ntile * 64 + nf * 16 + l15;
                atomicAdd(&num_r[(size_t)d * DIM + col], w * accr[nf][j]);
                atomicAdd(&num_i[(size_t)d * DIM + col], w * acci[nf][j]);
            }
        }
    }
}

__global__ void finalize_kernel(float* __restrict__ out,
                                const float* __restrict__ denom) {
    int idx = blockIdx.x * 256 + threadIdx.x;
    if (idx >= (2 * N_ENT * DIM) / 4) return;
    int rowid = idx >> 5;
    int v = (rowid < N_ENT) ? rowid : rowid - N_ENT;
    float inv = 1.0f / (denom[v] + 1e-10f);
    float4* p = reinterpret_cast<float4*>(out + OUT_ER) + idx;
    float4 x = *p;
    x.x = tanhf(x.x * inv);
    x.y = tanhf(x.y * inv);
    x.z = tanhf(x.z * inv);
    x.w = tanhf(x.w * inv);
    *p = x;
}

__global__ void gather_kernel(const int* __restrict__ sub,
                              const int* __restrict__ rel,
                              const float* __restrict__ relor,
                              const float* __restrict__ reloi,
                              float* __restrict__ out) {
    int idx = blockIdx.x * 256 + threadIdx.x;
    if (idx >= 4 * BATCH_Q * 32) return;
    int arr = idx >> 17;
    int rem = idx & 131071;
    int b = rem >> 5, c = rem & 31;
    const float* srcp;
    float* dstp;
    if (arr == 0)      { srcp = out + OUT_ER + (size_t)sub[b] * DIM; dstp = out + OUT_SUBR; }
    else if (arr == 1) { srcp = out + OUT_EI + (size_t)sub[b] * DIM; dstp = out + OUT_SUBI; }
    else if (arr == 2) { srcp = relor + (size_t)rel[b] * DIM;        dstp = out + OUT_RELR; }
    else               { srcp = reloi + (size_t)rel[b] * DIM;        dstp = out + OUT_RELI; }
    reinterpret_cast<float4*>(dstp + (size_t)b * DIM)[c] =
        reinterpret_cast<const float4*>(srcp)[c];
}

extern "C" void kernel_launch(void* const* d_in, const int* in_sizes, int n_in,
                              void* d_out, int out_size, void* d_ws, size_t ws_size,
                              hipStream_t stream) {
    const int*   eidx    = (const int*)d_in[0];
    const int*   etype   = (const int*)d_in[1];
    const int*   sub     = (const int*)d_in[2];
    const int*   rel     = (const int*)d_in[3];
    const float* emb_r   = (const float*)d_in[4];
    const float* emb_i   = (const float*)d_in[5];
    const float* relreal = (const float*)d_in[6];
    const float* relimag = (const float*)d_in[7];
    const float* im_proj = (const float*)d_in[8];
    const float* w_real  = (const float*)d_in[9];
    const float* w_imag  = (const float*)d_in[10];
    const float* w_rel   = (const float*)d_in[11];
    const float* att_a   = (const float*)d_in[12];

    float* out = (float*)d_out;
    float* ws  = (float*)d_ws;

    float* ent_i  = ws + WS_ENTI;
    float* rel_i  = ws + WS_RELI;
    float* relor  = ws + WS_RELOR;
    float* reloi  = ws + WS_RELOI;
    float* denom  = ws + WS_DENOM;
    __hip_bfloat16* wb  = reinterpret_cast<__hip_bfloat16*>(ws + WS_BF16);
    __hip_bfloat16* Pb  = wb;
    unsigned short* Wtr = reinterpret_cast<unsigned short*>(wb + 16384);
    unsigned short* Wti = reinterpret_cast<unsigned short*>(wb + 32768);

    // sort scratch aliased into d_out[0 .. OUT_ER): only gather (last kernel)
    // writes that region.
    int* outi = (int*)d_out;
    int* sp  = outi;                // 500000
    int* sd  = outi + N_EDGE;       // 500000
    int* cnt = outi + 2 * N_EDGE;   // 100000

    hipMemsetAsync(out + OUT_ER, 0, (size_t)(2 * N_ENT * DIM) * sizeof(float), stream);
    hipMemsetAsync(denom, 0, (size_t)N_ENT * sizeof(float), stream);
    hipMemsetAsync(cnt, 0, (size_t)N_ENT * sizeof(int), stream);

    convert_w<<<192, 256, 0, stream>>>(im_proj, w_real, w_imag, wb);
    hist_kernel<<<(N_EDGE + 255) / 256, 256, 0, stream>>>(eidx, cnt);
    scan_kernel<<<1, 1024, 0, stream>>>(cnt);
    scatter_kernel<<<(N_EDGE + 255) / 256, 256, 0, stream>>>(eidx, etype, cnt, sp, sd);
    proj_ent<<<1563, 512, 0, stream>>>(emb_i, Pb, ent_i);
    rel_kernel<<<474, 128, 0, stream>>>(relreal, relimag, im_proj, w_rel,
                                        rel_i, relor, reloi);
    edge_kernel<<<7813, 512, 0, stream>>>(sp, sd, emb_r, ent_i,
                                          relreal, rel_i, Wtr, Wti, att_a,
                                          out + OUT_ER, out + OUT_EI, denom);
    finalize_kernel<<<25000, 256, 0, stream>>>(out, denom);
    gather_kernel<<<2048, 256, 0, stream>>>(sub, rel, relor, reloi, out);
}

// Round 4
// 662.046 us; speedup vs baseline: 3.1527x; 1.9921x over previous
//
#include <hip/hip_runtime.h>
#include <hip/hip_bf16.h>

#define N_ENT   100000
#define N_RELT  474        // 2*237
#define DIM     128
#define N_EDGE  500000
#define BATCH_Q 4096

typedef __attribute__((ext_vector_type(8))) short short8v;   // 8 bf16 (4 VGPRs)
typedef __attribute__((ext_vector_type(4))) float f32x4;

// ---- output layout (float offsets) ----
#define OUT_SUBR 0
#define OUT_SUBI (BATCH_Q * DIM)          // 524288
#define OUT_RELR (2 * BATCH_Q * DIM)      // 1048576
#define OUT_RELI (3 * BATCH_Q * DIM)      // 1572864
#define OUT_ER   (4 * BATCH_Q * DIM)      // 2097152
#define OUT_EI   (OUT_ER + N_ENT * DIM)   // 14897152
// d_out[0 .. 2097152) is scratch until gather_kernel (the final kernel):
// sp (500K int), sd (500K int), eo (100K int: end offsets after scatter).

// ---- workspace layout (float/int offsets) ----
#define WS_ENTI  0
#define WS_RELI  (N_ENT * DIM)                 // 12800000
#define WS_RELOR (WS_RELI + N_RELT * DIM)
#define WS_RELOI (WS_RELOR + N_RELT * DIM)
#define WS_DENOM (WS_RELOI + N_RELT * DIM)     // N_ENT floats
#define WS_LIST  (WS_DENOM + N_ENT)            // 16384 ints (boundary vertex list)
#define WS_CNT2  (WS_LIST + 16384)             // 64 ints (list counter)
#define WS_BSUM  (WS_CNT2 + 64)                // 128 ints (scan block sums)
#define WS_BF16  (WS_BSUM + 128)               // bf16: Pb(16384) Wtr(16384) Wti(16384)

__device__ __forceinline__ unsigned int pack2bf(float a, float b) {
    return (__float_as_uint(a) >> 16) | (__float_as_uint(b) & 0xFFFF0000u);
}
__device__ __forceinline__ unsigned short f2bf(float a) {
    return (unsigned short)(__float_as_uint(a) >> 16);
}
__device__ __forceinline__ float bf2f(unsigned short u) {
    return __uint_as_float(((unsigned int)u) << 16);
}

// Pb = bf16(im_proj) [k][j]; Wtr/Wti = bf16 TRANSPOSED: Wt[n][k] = W[k][n]
__global__ void convert_w(const float* __restrict__ P,
                          const float* __restrict__ Wr,
                          const float* __restrict__ Wi,
                          __hip_bfloat16* __restrict__ dst) {
    int i = blockIdx.x * 256 + threadIdx.x;   // 49152 total
    if (i < 16384) {
        dst[i] = __float2bfloat16(P[i]);
    } else if (i < 32768) {
        int j = i - 16384; int n = j >> 7, k = j & 127;
        dst[i] = __float2bfloat16(Wr[k * 128 + n]);
    } else if (i < 49152) {
        int j = i - 32768; int n = j >> 7, k = j & 127;
        dst[i] = __float2bfloat16(Wi[k * 128 + n]);
    }
}

// ---------------- counting sort by destination ----------------
__global__ void hist_kernel(const int* __restrict__ eidx, int* __restrict__ cnt) {
    int e = blockIdx.x * 256 + threadIdx.x;
    if (e < N_EDGE) atomicAdd(&cnt[eidx[N_EDGE + e]], 1);
}

// hierarchical coalesced scan: scan1 (per-1024 block) -> scan2 (block sums) -> scan3 (add)
__global__ void scan1_kernel(int* __restrict__ cnt, int* __restrict__ bsums) {
    __shared__ int s[1024];
    const int t = threadIdx.x;
    const int gid = blockIdx.x * 1024 + t;
    int v = (gid < N_ENT) ? cnt[gid] : 0;
    s[t] = v;
    __syncthreads();
    for (int off = 1; off < 1024; off <<= 1) {
        int u = (t >= off) ? s[t - off] : 0;
        __syncthreads();
        s[t] += u;
        __syncthreads();
    }
    if (gid < N_ENT) cnt[gid] = s[t] - v;          // exclusive within block
    if (t == 1023) bsums[blockIdx.x] = s[t];       // block total
}

__global__ void scan2_kernel(int* __restrict__ bsums) {   // 98 values, 128 threads
    __shared__ int s[128];
    const int t = threadIdx.x;
    int v = (t < 98) ? bsums[t] : 0;
    s[t] = v;
    __syncthreads();
    for (int off = 1; off < 128; off <<= 1) {
        int u = (t >= off) ? s[t - off] : 0;
        __syncthreads();
        s[t] += u;
        __syncthreads();
    }
    if (t < 98) bsums[t] = s[t] - v;               // exclusive
}

__global__ void scan3_kernel(int* __restrict__ cnt, const int* __restrict__ bsums) {
    const int gid = blockIdx.x * 1024 + threadIdx.x;
    if (gid < N_ENT) cnt[gid] += bsums[blockIdx.x];
}

__global__ void scatter_kernel(const int* __restrict__ eidx,
                               const int* __restrict__ etype,
                               int* __restrict__ cursor,
                               int* __restrict__ sp,   // src | et<<17
                               int* __restrict__ sd) { // dst (nondecreasing)
    int e = blockIdx.x * 256 + threadIdx.x;
    if (e >= N_EDGE) return;
    int d = eidx[N_EDGE + e];
    int p = atomicAdd(&cursor[d], 1);
    sp[p] = eidx[e] | (etype[e] << 17);
    sd[p] = d;
}
// after scatter_kernel, cursor[v] == end offset of vertex v (eo array)

// ent_i = init_embed_imag @ im_proj   [100000,128] @ [128,128]
__launch_bounds__(512, 4)
__global__ void proj_ent(const float* __restrict__ imag,
                         const __hip_bfloat16* __restrict__ Pb,
                         float* __restrict__ ent_i) {
    __shared__ __align__(16) float sx[64 * 128];
    const int t = threadIdx.x;
    const int base = blockIdx.x * 64;
    for (int i = t; i < 64 * 128; i += 512) {
        int r = i >> 7, k = i & 127;
        int gr = base + r;
        sx[i] = (gr < N_ENT) ? imag[(size_t)gr * DIM + k] : 0.f;
    }
    __syncthreads();
    const int lane = t & 63, g = t >> 6;
    const int j0 = lane, j1 = lane + 64;
    float y0[8], y1[8];
#pragma unroll
    for (int e = 0; e < 8; ++e) { y0[e] = 0.f; y1[e] = 0.f; }
    for (int k = 0; k < 128; k += 4) {
        float p0[4], p1[4];
#pragma unroll
        for (int q = 0; q < 4; ++q) {
            p0[q] = __bfloat162float(Pb[(k + q) * 128 + j0]);
            p1[q] = __bfloat162float(Pb[(k + q) * 128 + j1]);
        }
#pragma unroll
        for (int e = 0; e < 8; ++e) {
            const float4 xv = *reinterpret_cast<const float4*>(&sx[(g * 8 + e) * 128 + k]);
            y0[e] = fmaf(xv.x, p0[0], y0[e]); y0[e] = fmaf(xv.y, p0[1], y0[e]);
            y0[e] = fmaf(xv.z, p0[2], y0[e]); y0[e] = fmaf(xv.w, p0[3], y0[e]);
            y1[e] = fmaf(xv.x, p1[0], y1[e]); y1[e] = fmaf(xv.y, p1[1], y1[e]);
            y1[e] = fmaf(xv.z, p1[2], y1[e]); y1[e] = fmaf(xv.w, p1[3], y1[e]);
        }
    }
#pragma unroll
    for (int e = 0; e < 8; ++e) {
        int gr = base + g * 8 + e;
        if (gr < N_ENT) {
            ent_i[(size_t)gr * DIM + j0] = y0[e];
            ent_i[(size_t)gr * DIM + j1] = y1[e];
        }
    }
}

__global__ void rel_kernel(const float* __restrict__ rel_real,
                           const float* __restrict__ rel_imag,
                           const float* __restrict__ P,
                           const float* __restrict__ Wrel,
                           float* __restrict__ rel_i,
                           float* __restrict__ rel_or,
                           float* __restrict__ rel_oi) {
    __shared__ float s_im[128], s_re[128], s_ri[128];
    const int j = threadIdx.x;
    const int r = blockIdx.x;
    s_im[j] = rel_imag[r * 128 + j];
    s_re[j] = rel_real[r * 128 + j];
    __syncthreads();
    float acc = 0.f;
    for (int k = 0; k < 128; ++k) acc = fmaf(s_im[k], P[k * 128 + j], acc);
    rel_i[r * 128 + j] = acc;
    s_ri[j] = acc;
    __syncthreads();
    float ai = 0.f, ar = 0.f;
    for (int k = 0; k < 128; ++k) {
        float w = Wrel[k * 128 + j];
        ai = fmaf(s_ri[k], w, ai);
        ar = fmaf(s_re[k], w, ar);
    }
    rel_oi[r * 128 + j] = tanhf(ai);
    rel_or[r * 128 + j] = tanhf(ar);
}

// ---------------- MFMA edge kernel + in-block segmented reduction ----------------
// 64 dst-sorted edges/block. m (bf16 XOR-swizzled) in LDS; h = m @ W via
// mfma_f32_16x16x32_bf16. After MFMA the m buffer is dead, so an ex-weighted
// h buffer (hw, bf16, [64][260]) UNIONs with it. 256 column-threads then walk
// the 64 rows summing per-dst runs: interior vertices -> direct final
// tanh(num/den) store (no atomics); boundary runs (<=2/block) -> f32 atomics,
// finished by boundary_finalize.
__launch_bounds__(512, 6)
__global__ void edge_kernel(const int* __restrict__ sp,
                            const int* __restrict__ sd,
                            const float* __restrict__ ent_r,
                            const float* __restrict__ ent_i,
                            const float* __restrict__ rel_r,
                            const float* __restrict__ rel_i,
                            const unsigned short* __restrict__ Wtr,
                            const unsigned short* __restrict__ Wti,
                            const float* __restrict__ att_a,
                            float* __restrict__ num_r,
                            float* __restrict__ num_i,
                            float* __restrict__ denw) {
    __shared__ __align__(16) unsigned short u_sh[16640];  // union: m (16384) / hw (64*260)
    __shared__ float plog[64][2];
    __shared__ float exl[64];
    __shared__ int s_se[64], s_dst[64];
    __shared__ int s_flags[2];
    unsigned short* m_r_sh = u_sh;            // [64*128]
    unsigned short* m_i_sh = u_sh + 8192;     // [64*128]

    const int t = threadIdx.x;
    const int base = blockIdx.x * 64;

    if (t < 64) {
        int ge = base + t;
        bool ok = ge < N_EDGE;
        s_se[t]  = ok ? sp[ge] : 0;
        s_dst[t] = ok ? sd[ge] : -1;
    }
    if (t == 0) s_flags[0] = (base > 0 && sd[base - 1] == sd[base]) ? 1 : 0;
    if (t == 1) { int ge = base + 64; s_flags[1] = (ge < N_EDGE && sd[ge - 1] == sd[ge]) ? 1 : 0; }
    __syncthreads();

    // stage m as bf16, chunk-swizzled: chunk c of row e stored at (c ^ (e&15))
    for (int it = 0; it < 2; ++it) {
        int i = t + it * 512;
        int e = i >> 4, c = i & 15;
        bool ok = (base + e) < N_EDGE;
        int pk = s_se[e];
        int src = pk & 0x1FFFF, et = pk >> 17;
        const float* pr = ent_r + (size_t)src * DIM + c * 8;
        const float* pi = ent_i + (size_t)src * DIM + c * 8;
        const float* qr = rel_r + (size_t)et * DIM + c * 8;
        const float* qi = rel_i + (size_t)et * DIM + c * 8;
        float4 er0 = reinterpret_cast<const float4*>(pr)[0];
        float4 er1 = reinterpret_cast<const float4*>(pr)[1];
        float4 ei0 = reinterpret_cast<const float4*>(pi)[0];
        float4 ei1 = reinterpret_cast<const float4*>(pi)[1];
        float4 rr0 = reinterpret_cast<const float4*>(qr)[0];
        float4 rr1 = reinterpret_cast<const float4*>(qr)[1];
        float4 ri0 = reinterpret_cast<const float4*>(qi)[0];
        float4 ri1 = reinterpret_cast<const float4*>(qi)[1];
        float r[8], im[8];
        r[0] = er0.x*rr0.x - ei0.x*ri0.x;  im[0] = er0.x*ri0.x + ei0.x*rr0.x;
        r[1] = er0.y*rr0.y - ei0.y*ri0.y;  im[1] = er0.y*ri0.y + ei0.y*rr0.y;
        r[2] = er0.z*rr0.z - ei0.z*ri0.z;  im[2] = er0.z*ri0.z + ei0.z*rr0.z;
        r[3] = er0.w*rr0.w - ei0.w*ri0.w;  im[3] = er0.w*ri0.w + ei0.w*rr0.w;
        r[4] = er1.x*rr1.x - ei1.x*ri1.x;  im[4] = er1.x*ri1.x + ei1.x*rr1.x;
        r[5] = er1.y*rr1.y - ei1.y*ri1.y;  im[5] = er1.y*ri1.y + ei1.y*rr1.y;
        r[6] = er1.z*rr1.z - ei1.z*ri1.z;  im[6] = er1.z*ri1.z + ei1.z*rr1.z;
        r[7] = er1.w*rr1.w - ei1.w*ri1.w;  im[7] = er1.w*ri1.w + ei1.w*rr1.w;
        uint4 ur, ui;
        if (ok) {
            ur.x = pack2bf(r[0], r[1]); ur.y = pack2bf(r[2], r[3]);
            ur.z = pack2bf(r[4], r[5]); ur.w = pack2bf(r[6], r[7]);
            ui.x = pack2bf(im[0], im[1]); ui.y = pack2bf(im[2], im[3]);
            ui.z = pack2bf(im[4], im[5]); ui.w = pack2bf(im[6], im[7]);
        } else {
            ur.x = ur.y = ur.z = ur.w = 0u;
            ui.x = ui.y = ui.z = ui.w = 0u;
        }
        int idx = e * 128 + ((c ^ (e & 15)) << 3);
        *reinterpret_cast<uint4*>(&m_r_sh[idx]) = ur;
        *reinterpret_cast<uint4*>(&m_i_sh[idx]) = ui;
    }
    __syncthreads();

    const int lane = t & 63, g = t >> 6;
    const int mtile = g & 3, ntile = g >> 2;
    const int l15 = lane & 15, l4 = lane >> 4;
    const int arow = mtile * 16 + l15;

    f32x4 accr[4], acci[4];
#pragma unroll
    for (int nf = 0; nf < 4; ++nf) {
        accr[nf] = (f32x4){0.f, 0.f, 0.f, 0.f};
        acci[nf] = (f32x4){0.f, 0.f, 0.f, 0.f};
    }
#pragma unroll
    for (int ks = 0; ks < 4; ++ks) {
        int chunkx = (ks * 4 + l4) ^ l15;
        int aidx = arow * 128 + chunkx * 8;
        short8v a_r = *reinterpret_cast<const short8v*>(&m_r_sh[aidx]);
        short8v a_i = *reinterpret_cast<const short8v*>(&m_i_sh[aidx]);
        int kb = ks * 32 + l4 * 8;
#pragma unroll
        for (int nf = 0; nf < 4; ++nf) {
            int n = ntile * 64 + nf * 16 + l15;
            short8v b_r = *reinterpret_cast<const short8v*>(&Wtr[n * 128 + kb]);
            short8v b_i = *reinterpret_cast<const short8v*>(&Wti[n * 128 + kb]);
            accr[nf] = __builtin_amdgcn_mfma_f32_16x16x32_bf16(a_r, b_r, accr[nf], 0, 0, 0);
            acci[nf] = __builtin_amdgcn_mfma_f32_16x16x32_bf16(a_i, b_i, acci[nf], 0, 0, 0);
        }
    }

    // logits: partial over this wave's 64 cols, butterfly over 16 lanes
    float pj[4] = {0.f, 0.f, 0.f, 0.f};
#pragma unroll
    for (int nf = 0; nf < 4; ++nf) {
        int n = ntile * 64 + nf * 16 + l15;
        float ar = att_a[n], ai = att_a[128 + n];
#pragma unroll
        for (int j = 0; j < 4; ++j)
            pj[j] += accr[nf][j] * ar + acci[nf][j] * ai;
    }
#pragma unroll
    for (int off = 1; off < 16; off <<= 1) {
#pragma unroll
        for (int j = 0; j < 4; ++j) pj[j] += __shfl_xor(pj[j], off, 64);
    }
    if (l15 == 0) {
#pragma unroll
        for (int j = 0; j < 4; ++j)
            plog[mtile * 16 + l4 * 4 + j][ntile] = pj[j];
    }
    __syncthreads();

    if (t < 64) {
        float lg = plog[t][0] + plog[t][1];
        lg = lg > 0.f ? lg : 0.2f * lg;       // leaky_relu(0.2)
        exl[t] = expf(lg);                    // logits ~1e-3: no max-shift needed
    }
    __syncthreads();   // exl ready; all MFMA done -> m buffer is dead, reuse as hw

    // write ex-weighted h into hw[row][col] (bf16, stride 260: conflict-free)
#pragma unroll
    for (int j = 0; j < 4; ++j) {
        int row = mtile * 16 + l4 * 4 + j;
        float w = exl[row];
#pragma unroll
        for (int nf = 0; nf < 4; ++nf) {
            int col = ntile * 64 + nf * 16 + l15;
            u_sh[row * 260 + col]       = f2bf(w * accr[nf][j]);
            u_sh[row * 260 + 128 + col] = f2bf(w * acci[nf][j]);
        }
    }
    __syncthreads();

    // segmented reduction over dst runs: 256 column-threads walk 64 rows
    if (t < 256) {
        const int c = t;
        const int cc = c & 127;
        float* plane = (c < 128) ? num_r : num_i;
        const int fs = s_flags[0], ls = s_flags[1];
        float num = 0.f, den = 0.f;
        int dprev = -1, rstart = 0;
        for (int r = 0; r < 64; ++r) {
            int d = s_dst[r];
            if (d != dprev) {
                if (dprev >= 0) {
                    if (rstart == 0 && fs) {           // run shared with prev block
                        atomicAdd(&plane[(size_t)dprev * DIM + cc], num);
                        if (c == 0) atomicAdd(&denw[dprev], den);
                    } else {
                        plane[(size_t)dprev * DIM + cc] = tanhf(num / (den + 1e-10f));
                    }
                }
                dprev = d; num = 0.f; den = 0.f; rstart = r;
            }
            num += bf2f(u_sh[r * 260 + c]);
            den += exl[r];
        }
        if (dprev >= 0) {
            bool isb = (rstart == 0 && fs) || ls;      // final run reaches row 63
            if (isb) {
                atomicAdd(&plane[(size_t)dprev * DIM + cc], num);
                if (c == 0) atomicAdd(&denw[dprev], den);
            } else {
                plane[(size_t)dprev * DIM + cc] = tanhf(num / (den + 1e-10f));
            }
        }
    }
}

// mark vertices whose edge run crosses a 64-edge block boundary
__global__ void classify_kernel(const int* __restrict__ eo,
                                int* __restrict__ list,
                                int* __restrict__ cnt2) {
    int v = blockIdx.x * 256 + threadIdx.x;
    if (v >= N_ENT) return;
    int start = v ? eo[v - 1] : 0;
    int end = eo[v];
    if (end > start && ((start >> 6) != ((end - 1) >> 6))) {
        int i = atomicAdd(cnt2, 1);
        if (i < 16384) list[i] = v;
    }
}

__global__ void boundary_finalize(const int* __restrict__ list,
                                  const int* __restrict__ cnt2,
                                  const float* __restrict__ denw,
                                  float* __restrict__ er,
                                  float* __restrict__ ei) {
    int j = blockIdx.x;
    if (j >= cnt2[0]) return;
    int v = list[j];
    int c = threadIdx.x;                 // 256
    float den = denw[v] + 1e-10f;
    float* plane = (c < 128) ? er : ei;
    size_t idx = (size_t)v * DIM + (c & 127);
    plane[idx] = tanhf(plane[idx] / den);
}

__global__ void gather_kernel(const int* __restrict__ sub,
                              const int* __restrict__ rel,
                              const float* __restrict__ relor,
                              const float* __restrict__ reloi,
                              float* __restrict__ out) {
    int idx = blockIdx.x * 256 + threadIdx.x;
    if (idx >= 4 * BATCH_Q * 32) return;
    int arr = idx >> 17;
    int rem = idx & 131071;
    int b = rem >> 5, c = rem & 31;
    const float* srcp;
    float* dstp;
    if (arr == 0)      { srcp = out + OUT_ER + (size_t)sub[b] * DIM; dstp = out + OUT_SUBR; }
    else if (arr == 1) { srcp = out + OUT_EI + (size_t)sub[b] * DIM; dstp = out + OUT_SUBI; }
    else if (arr == 2) { srcp = relor + (size_t)rel[b] * DIM;        dstp = out + OUT_RELR; }
    else               { srcp = reloi + (size_t)rel[b] * DIM;        dstp = out + OUT_RELI; }
    reinterpret_cast<float4*>(dstp + (size_t)b * DIM)[c] =
        reinterpret_cast<const float4*>(srcp)[c];
}

extern "C" void kernel_launch(void* const* d_in, const int* in_sizes, int n_in,
                              void* d_out, int out_size, void* d_ws, size_t ws_size,
                              hipStream_t stream) {
    const int*   eidx    = (const int*)d_in[0];
    const int*   etype   = (const int*)d_in[1];
    const int*   sub     = (const int*)d_in[2];
    const int*   rel     = (const int*)d_in[3];
    const float* emb_r   = (const float*)d_in[4];
    const float* emb_i   = (const float*)d_in[5];
    const float* relreal = (const float*)d_in[6];
    const float* relimag = (const float*)d_in[7];
    const float* im_proj = (const float*)d_in[8];
    const float* w_real  = (const float*)d_in[9];
    const float* w_imag  = (const float*)d_in[10];
    const float* w_rel   = (const float*)d_in[11];
    const float* att_a   = (const float*)d_in[12];

    float* out = (float*)d_out;
    float* ws  = (float*)d_ws;
    int*   wsi = (int*)d_ws;

    float* ent_i  = ws + WS_ENTI;
    float* rel_i  = ws + WS_RELI;
    float* relor  = ws + WS_RELOR;
    float* reloi  = ws + WS_RELOI;
    float* denw   = ws + WS_DENOM;
    int*   list   = wsi + WS_LIST;
    int*   cnt2   = wsi + WS_CNT2;
    int*   bsums  = wsi + WS_BSUM;
    __hip_bfloat16* wb  = reinterpret_cast<__hip_bfloat16*>(ws + WS_BF16);
    __hip_bfloat16* Pb  = wb;
    unsigned short* Wtr = reinterpret_cast<unsigned short*>(wb + 16384);
    unsigned short* Wti = reinterpret_cast<unsigned short*>(wb + 32768);

    // sort scratch aliased into d_out[0 .. OUT_ER): gather (last) overwrites it
    int* outi = (int*)d_out;
    int* sp = outi;                // 500000
    int* sd = outi + N_EDGE;       // 500000
    int* eo = outi + 2 * N_EDGE;   // 100000 (hist cnt -> start offsets -> end offsets)

    hipMemsetAsync(out + OUT_ER, 0, (size_t)(2 * N_ENT * DIM) * sizeof(float), stream);
    hipMemsetAsync(denw, 0, (size_t)N_ENT * sizeof(float), stream);
    hipMemsetAsync(eo,   0, (size_t)N_ENT * sizeof(int), stream);
    hipMemsetAsync(cnt2, 0, 64 * sizeof(int), stream);

    convert_w<<<192, 256, 0, stream>>>(im_proj, w_real, w_imag, wb);
    hist_kernel<<<(N_EDGE + 255) / 256, 256, 0, stream>>>(eidx, eo);
    scan1_kernel<<<98, 1024, 0, stream>>>(eo, bsums);
    scan2_kernel<<<1, 128, 0, stream>>>(bsums);
    scan3_kernel<<<98, 1024, 0, stream>>>(eo, bsums);
    scatter_kernel<<<(N_EDGE + 255) / 256, 256, 0, stream>>>(eidx, etype, eo, sp, sd);
    proj_ent<<<1563, 512, 0, stream>>>(emb_i, Pb, ent_i);
    rel_kernel<<<474, 128, 0, stream>>>(relreal, relimag, im_proj, w_rel,
                                        rel_i, relor, reloi);
    edge_kernel<<<7813, 512, 0, stream>>>(sp, sd, emb_r, ent_i,
                                          relreal, rel_i, Wtr, Wti, att_a,
                                          out + OUT_ER, out + OUT_EI, denw);
    classify_kernel<<<(N_ENT + 255) / 256, 256, 0, stream>>>(eo, list, cnt2);
    boundary_finalize<<<7812, 256, 0, stream>>>(list, cnt2, denw,
                                                out + OUT_ER, out + OUT_EI);
    gather_kernel<<<2048, 256, 0, stream>>>(sub, rel, relor, reloi, out);
}

// Round 5
// 570.818 us; speedup vs baseline: 3.6566x; 1.1598x over previous
//
#include <hip/hip_runtime.h>
#include <hip/hip_bf16.h>

#define N_ENT   100000
#define N_RELT  474        // 2*237
#define DIM     128
#define N_EDGE  500000
#define BATCH_Q 4096

typedef __attribute__((ext_vector_type(8))) short short8v;   // 8 bf16 (4 VGPRs)
typedef __attribute__((ext_vector_type(4))) float f32x4;

// ---- output layout (float offsets) ----
#define OUT_SUBR 0
#define OUT_SUBI (BATCH_Q * DIM)          // 524288
#define OUT_RELR (2 * BATCH_Q * DIM)      // 1048576
#define OUT_RELI (3 * BATCH_Q * DIM)      // 1572864
#define OUT_ER   (4 * BATCH_Q * DIM)      // 2097152
#define OUT_EI   (OUT_ER + N_ENT * DIM)   // 14897152
// d_out[0 .. 2097152) is int scratch until gather_kernel (the final kernel):
#define SC_SP    0                         // 500000 (src|et<<17, dst-sorted)
#define SC_SD    N_EDGE                    // 500000 (dst, nondecreasing)
#define SC_EO    (2 * N_EDGE)              // 100000 (start offsets -> cursor)
#define SC_BLIST (2 * N_EDGE + N_ENT)      // 16384 boundary vertices
#define SC_ZLIST (SC_BLIST + 16384)        // 16384 rows to zero (empty+boundary)
#define SC_CNT   (SC_ZLIST + 16384)        // 64 ints: [0]=bcnt [1]=zcnt
#define SC_BSUM  (SC_CNT + 64)             // 128 ints (scan block sums)

// ---- workspace layout (float offsets) ----
#define WS_ENTIB 0                         // ushort[N_ENT*128]  (bf16 ent_i)
#define WS_ENTRB (N_ENT * DIM / 2)         // ushort[N_ENT*128] (bf16 ent_r)
#define WS_RELRB (2 * (N_ENT * DIM / 2))   // ushort[474*128]
#define WS_RELIB (WS_RELRB + N_RELT * DIM / 2)
#define WS_RELOR (WS_RELIB + N_RELT * DIM / 2)   // fp32 474*128
#define WS_RELOI (WS_RELOR + N_RELT * DIM)
#define WS_DENOM (WS_RELOI + N_RELT * DIM)       // N_ENT floats
#define WS_BF16  (WS_DENOM + N_ENT)              // ushort: Pb(16384) Wtr(16384) Wti(16384)

__device__ __forceinline__ unsigned int pack2bf(float a, float b) {
    return (__float_as_uint(a) >> 16) | (__float_as_uint(b) & 0xFFFF0000u);
}
__device__ __forceinline__ unsigned short f2bf(float a) {
    return (unsigned short)(__float_as_uint(a) >> 16);
}
__device__ __forceinline__ float bf2f(unsigned short u) {
    return __uint_as_float(((unsigned int)u) << 16);
}

// Pb = bf16(im_proj) [k][j]; Wtr/Wti = bf16 TRANSPOSED: Wt[n][k] = W[k][n]
__global__ void convert_w(const float* __restrict__ P,
                          const float* __restrict__ Wr,
                          const float* __restrict__ Wi,
                          unsigned short* __restrict__ dst) {
    int i = blockIdx.x * 256 + threadIdx.x;   // 49152 total
    if (i < 16384) {
        dst[i] = f2bf(P[i]);
    } else if (i < 32768) {
        int j = i - 16384; int n = j >> 7, k = j & 127;
        dst[i] = f2bf(Wr[k * 128 + n]);
    } else if (i < 49152) {
        int j = i - 32768; int n = j >> 7, k = j & 127;
        dst[i] = f2bf(Wi[k * 128 + n]);
    }
}

// ent_rb = bf16(init_embed_real), streamed 8 floats/thread
__global__ void convert_entr(const float* __restrict__ src,
                             unsigned short* __restrict__ dst) {
    int i = blockIdx.x * 256 + threadIdx.x;       // N_ENT*128/8 = 1,600,000
    if (i >= N_ENT * DIM / 8) return;
    const float4* s4 = reinterpret_cast<const float4*>(src);
    float4 a = s4[2 * i], b = s4[2 * i + 1];
    uint4 o;
    o.x = pack2bf(a.x, a.y); o.y = pack2bf(a.z, a.w);
    o.z = pack2bf(b.x, b.y); o.w = pack2bf(b.z, b.w);
    reinterpret_cast<uint4*>(dst)[i] = o;
}

// ---------------- counting sort by destination ----------------
__global__ void hist_kernel(const int* __restrict__ eidx, int* __restrict__ cnt) {
    int e = blockIdx.x * 256 + threadIdx.x;
    if (e < N_EDGE) atomicAdd(&cnt[eidx[N_EDGE + e]], 1);
}

__global__ void scan1_kernel(int* __restrict__ cnt, int* __restrict__ bsums) {
    __shared__ int s[1024];
    const int t = threadIdx.x;
    const int gid = blockIdx.x * 1024 + t;
    int v = (gid < N_ENT) ? cnt[gid] : 0;
    s[t] = v;
    __syncthreads();
    for (int off = 1; off < 1024; off <<= 1) {
        int u = (t >= off) ? s[t - off] : 0;
        __syncthreads();
        s[t] += u;
        __syncthreads();
    }
    if (gid < N_ENT) cnt[gid] = s[t] - v;          // exclusive within block
    if (t == 1023) bsums[blockIdx.x] = s[t];       // block total
}

__global__ void scan2_kernel(int* __restrict__ bsums) {   // 98 values
    __shared__ int s[128];
    const int t = threadIdx.x;
    int v = (t < 98) ? bsums[t] : 0;
    s[t] = v;
    __syncthreads();
    for (int off = 1; off < 128; off <<= 1) {
        int u = (t >= off) ? s[t - off] : 0;
        __syncthreads();
        s[t] += u;
        __syncthreads();
    }
    if (t < 98) bsums[t] = s[t] - v;               // exclusive
}

__global__ void scan3_kernel(int* __restrict__ cnt, const int* __restrict__ bsums) {
    const int gid = blockIdx.x * 1024 + threadIdx.x;
    if (gid < N_ENT) cnt[gid] += bsums[blockIdx.x];
}

// after scan3, eo[v] = START offset. Classify BEFORE scatter mutates eo.
__global__ void classify_pre(const int* __restrict__ eo,
                             int* __restrict__ blist,
                             int* __restrict__ zlist,
                             int* __restrict__ cnts) {
    int v = blockIdx.x * 256 + threadIdx.x;
    if (v >= N_ENT) return;
    int start = eo[v];
    int end = (v == N_ENT - 1) ? N_EDGE : eo[v + 1];
    bool empty = (end == start);
    bool bound = (end > start) && ((start >> 6) != ((end - 1) >> 6));
    if (bound) { int i = atomicAdd(&cnts[0], 1); if (i < 16384) blist[i] = v; }
    if (empty || bound) { int i = atomicAdd(&cnts[1], 1); if (i < 16384) zlist[i] = v; }
}

// zero only rows that need it (empty stay 0; boundary rows accumulate atomics)
__global__ void zero_rows(const int* __restrict__ zlist,
                          const int* __restrict__ cnts,
                          float* __restrict__ er, float* __restrict__ ei) {
    int j = blockIdx.x;
    if (j >= cnts[1]) return;
    int v = zlist[j];
    int c = threadIdx.x;                 // 256
    float* plane = (c < 128) ? er : ei;
    plane[(size_t)v * DIM + (c & 127)] = 0.f;
}

__global__ void scatter_kernel(const int* __restrict__ eidx,
                               const int* __restrict__ etype,
                               int* __restrict__ cursor,
                               int* __restrict__ sp,
                               int* __restrict__ sd) {
    int e = blockIdx.x * 256 + threadIdx.x;
    if (e >= N_EDGE) return;
    int d = eidx[N_EDGE + e];
    int p = atomicAdd(&cursor[d], 1);
    sp[p] = eidx[e] | (etype[e] << 17);
    sd[p] = d;
}

// ent_ib = bf16(init_embed_imag @ im_proj), cols paired (2*lane, 2*lane+1)
__launch_bounds__(512, 4)
__global__ void proj_ent(const float* __restrict__ imag,
                         const unsigned short* __restrict__ Pb,
                         unsigned short* __restrict__ ent_ib) {
    __shared__ __align__(16) float sx[64 * 128];
    const int t = threadIdx.x;
    const int base = blockIdx.x * 64;
    for (int i = t; i < 64 * 128; i += 512) {
        int r = i >> 7, k = i & 127;
        int gr = base + r;
        sx[i] = (gr < N_ENT) ? imag[(size_t)gr * DIM + k] : 0.f;
    }
    __syncthreads();
    const int lane = t & 63, g = t >> 6;
    float y0[8], y1[8];
#pragma unroll
    for (int e = 0; e < 8; ++e) { y0[e] = 0.f; y1[e] = 0.f; }
    for (int k = 0; k < 128; k += 4) {
        float p0[4], p1[4];
#pragma unroll
        for (int q = 0; q < 4; ++q) {
            unsigned int up = *reinterpret_cast<const unsigned int*>(&Pb[(k + q) * 128 + 2 * lane]);
            p0[q] = bf2f((unsigned short)(up & 0xFFFFu));
            p1[q] = bf2f((unsigned short)(up >> 16));
        }
#pragma unroll
        for (int e = 0; e < 8; ++e) {
            const float4 xv = *reinterpret_cast<const float4*>(&sx[(g * 8 + e) * 128 + k]);
            y0[e] = fmaf(xv.x, p0[0], y0[e]); y0[e] = fmaf(xv.y, p0[1], y0[e]);
            y0[e] = fmaf(xv.z, p0[2], y0[e]); y0[e] = fmaf(xv.w, p0[3], y0[e]);
            y1[e] = fmaf(xv.x, p1[0], y1[e]); y1[e] = fmaf(xv.y, p1[1], y1[e]);
            y1[e] = fmaf(xv.z, p1[2], y1[e]); y1[e] = fmaf(xv.w, p1[3], y1[e]);
        }
    }
#pragma unroll
    for (int e = 0; e < 8; ++e) {
        int gr = base + g * 8 + e;
        if (gr < N_ENT)
            *reinterpret_cast<unsigned int*>(&ent_ib[(size_t)gr * DIM + 2 * lane]) =
                pack2bf(y0[e], y1[e]);
    }
}

// relation path + bf16 copies of rel_r and rel_i for the edge gather
__global__ void rel_kernel(const float* __restrict__ rel_real,
                           const float* __restrict__ rel_imag,
                           const float* __restrict__ P,
                           const float* __restrict__ Wrel,
                           unsigned short* __restrict__ rel_rb,
                           unsigned short* __restrict__ rel_ib,
                           float* __restrict__ rel_or,
                           float* __restrict__ rel_oi) {
    __shared__ float s_im[128], s_re[128], s_ri[128];
    const int j = threadIdx.x;
    const int r = blockIdx.x;
    s_im[j] = rel_imag[r * 128 + j];
    s_re[j] = rel_real[r * 128 + j];
    __syncthreads();
    float acc = 0.f;
    for (int k = 0; k < 128; ++k) acc = fmaf(s_im[k], P[k * 128 + j], acc);
    rel_ib[r * 128 + j] = f2bf(acc);
    rel_rb[r * 128 + j] = f2bf(s_re[j]);
    s_ri[j] = acc;
    __syncthreads();
    float ai = 0.f, ar = 0.f;
    for (int k = 0; k < 128; ++k) {
        float w = Wrel[k * 128 + j];
        ai = fmaf(s_ri[k], w, ai);
        ar = fmaf(s_re[k], w, ar);
    }
    rel_oi[r * 128 + j] = tanhf(ai);
    rel_or[r * 128 + j] = tanhf(ar);
}

// ---------------- MFMA edge kernel + in-block segmented reduction ----------------
// 64 dst-sorted edges/block; all tables bf16 (gather bytes halved vs fp32).
// Wave g owns a DISTINCT 16-col W panel (no intra-block W redundancy) and
// iterates all 4 m-tiles: 32 MFMA/wave, B-frag loads 64 KB/block (was 256 KB).
#define COMPOSE(eru, eiu, rru, riu, mro, mio) {                                   \
    float er_a = __uint_as_float((eru) << 16), er_b = __uint_as_float((eru) & 0xFFFF0000u); \
    float ei_a = __uint_as_float((eiu) << 16), ei_b = __uint_as_float((eiu) & 0xFFFF0000u); \
    float rr_a = __uint_as_float((rru) << 16), rr_b = __uint_as_float((rru) & 0xFFFF0000u); \
    float ri_a = __uint_as_float((riu) << 16), ri_b = __uint_as_float((riu) & 0xFFFF0000u); \
    mro = pack2bf(er_a * rr_a - ei_a * ri_a, er_b * rr_b - ei_b * ri_b);          \
    mio = pack2bf(er_a * ri_a + ei_a * rr_a, er_b * ri_b + ei_b * rr_b); }

__launch_bounds__(512, 6)
__global__ void edge_kernel(const int* __restrict__ sp,
                            const int* __restrict__ sd,
                            const unsigned short* __restrict__ ent_rb,
                            const unsigned short* __restrict__ ent_ib,
                            const unsigned short* __restrict__ rel_rb,
                            const unsigned short* __restrict__ rel_ib,
                            const unsigned short* __restrict__ Wtr,
                            const unsigned short* __restrict__ Wti,
                            const float* __restrict__ att_a,
                            float* __restrict__ num_r,
                            float* __restrict__ num_i,
                            float* __restrict__ denw) {
    __shared__ __align__(16) unsigned short u_sh[16640];  // union: m (16384) / hw [64][260]
    __shared__ float plog[64][8];
    __shared__ float exl[64];
    __shared__ int s_se[64], s_dst[64];
    __shared__ int s_flags[2];
    unsigned short* m_r_sh = u_sh;            // [64*128]
    unsigned short* m_i_sh = u_sh + 8192;     // [64*128]

    const int t = threadIdx.x;
    const int base = blockIdx.x * 64;

    if (t < 64) {
        int ge = base + t;
        bool ok = ge < N_EDGE;
        s_se[t]  = ok ? sp[ge] : 0;
        s_dst[t] = ok ? sd[ge] : -1;
    }
    if (t == 0) s_flags[0] = (base > 0 && sd[base - 1] == sd[base]) ? 1 : 0;
    if (t == 1) { int ge = base + 64; s_flags[1] = (ge < N_EDGE && sd[ge - 1] == sd[ge]) ? 1 : 0; }
    __syncthreads();

    // stage m as bf16 from bf16 tables; chunk c (8 elems) stored at (c ^ (e&15))
    for (int it = 0; it < 2; ++it) {
        int i = t + it * 512;
        int e = i >> 4, c = i & 15;
        bool ok = (base + e) < N_EDGE;
        int pk = s_se[e];
        int src = pk & 0x1FFFF, et = pk >> 17;
        uint4 erv = *reinterpret_cast<const uint4*>(&ent_rb[(size_t)src * DIM + c * 8]);
        uint4 eiv = *reinterpret_cast<const uint4*>(&ent_ib[(size_t)src * DIM + c * 8]);
        uint4 rrv = *reinterpret_cast<const uint4*>(&rel_rb[et * DIM + c * 8]);
        uint4 riv = *reinterpret_cast<const uint4*>(&rel_ib[et * DIM + c * 8]);
        uint4 mr, mi;
        COMPOSE(erv.x, eiv.x, rrv.x, riv.x, mr.x, mi.x);
        COMPOSE(erv.y, eiv.y, rrv.y, riv.y, mr.y, mi.y);
        COMPOSE(erv.z, eiv.z, rrv.z, riv.z, mr.z, mi.z);
        COMPOSE(erv.w, eiv.w, rrv.w, riv.w, mr.w, mi.w);
        if (!ok) { mr.x = mr.y = mr.z = mr.w = 0u; mi.x = mi.y = mi.z = mi.w = 0u; }
        int idx = e * 128 + ((c ^ (e & 15)) << 3);
        *reinterpret_cast<uint4*>(&m_r_sh[idx]) = mr;
        *reinterpret_cast<uint4*>(&m_i_sh[idx]) = mi;
    }
    __syncthreads();

    const int lane = t & 63, g = t >> 6;       // wave g owns cols g*16..g*16+15
    const int l15 = lane & 15, l4 = lane >> 4;
    const int ncol = g * 16 + l15;

    f32x4 accr[4], acci[4];
#pragma unroll
    for (int mt = 0; mt < 4; ++mt) {
        accr[mt] = (f32x4){0.f, 0.f, 0.f, 0.f};
        acci[mt] = (f32x4){0.f, 0.f, 0.f, 0.f};
    }
#pragma unroll
    for (int ks = 0; ks < 4; ++ks) {
        int kb = ks * 32 + l4 * 8;
        short8v b_r = *reinterpret_cast<const short8v*>(&Wtr[ncol * 128 + kb]);
        short8v b_i = *reinterpret_cast<const short8v*>(&Wti[ncol * 128 + kb]);
        int chunkx = (ks * 4 + l4) ^ l15;
#pragma unroll
        for (int mt = 0; mt < 4; ++mt) {
            int aidx = (mt * 16 + l15) * 128 + chunkx * 8;
            short8v a_r = *reinterpret_cast<const short8v*>(&m_r_sh[aidx]);
            short8v a_i = *reinterpret_cast<const short8v*>(&m_i_sh[aidx]);
            accr[mt] = __builtin_amdgcn_mfma_f32_16x16x32_bf16(a_r, b_r, accr[mt], 0, 0, 0);
            acci[mt] = __builtin_amdgcn_mfma_f32_16x16x32_bf16(a_i, b_i, acci[mt], 0, 0, 0);
        }
    }

    // logit partials: each lane holds one col; butterfly over the 16-lane group
    const float a_r = att_a[ncol], a_i = att_a[128 + ncol];
    float pj[4][4];
#pragma unroll
    for (int mt = 0; mt < 4; ++mt)
#pragma unroll
        for (int j = 0; j < 4; ++j)
            pj[mt][j] = accr[mt][j] * a_r + acci[mt][j] * a_i;
#pragma unroll
    for (int off = 1; off < 16; off <<= 1) {
#pragma unroll
        for (int mt = 0; mt < 4; ++mt)
#pragma unroll
            for (int j = 0; j < 4; ++j)
                pj[mt][j] += __shfl_xor(pj[mt][j], off, 64);
    }
    if (l15 == 0) {
#pragma unroll
        for (int mt = 0; mt < 4; ++mt)
#pragma unroll
            for (int j = 0; j < 4; ++j)
                plog[mt * 16 + l4 * 4 + j][g] = pj[mt][j];
    }
    __syncthreads();

    if (t < 64) {
        float lg = plog[t][0] + plog[t][1] + plog[t][2] + plog[t][3]
                 + plog[t][4] + plog[t][5] + plog[t][6] + plog[t][7];
        lg = lg > 0.f ? lg : 0.2f * lg;       // leaky_relu(0.2)
        exl[t] = expf(lg);                    // logits ~1e-3: no max-shift needed
    }
    __syncthreads();   // all MFMA done -> m buffer dead, reuse as hw

    // hw[row][col r | 128+col i], stride 260
#pragma unroll
    for (int mt = 0; mt < 4; ++mt)
#pragma unroll
        for (int j = 0; j < 4; ++j) {
            int row = mt * 16 + l4 * 4 + j;
            float w = exl[row];
            u_sh[row * 260 + ncol]       = f2bf(w * accr[mt][j]);
            u_sh[row * 260 + 128 + ncol] = f2bf(w * acci[mt][j]);
        }
    __syncthreads();

    // segmented reduction: 256 column-threads walk 64 rows; interior runs ->
    // direct final tanh(num/den) store; boundary runs -> f32 atomics
    if (t < 256) {
        const int c = t;
        const int cc = c & 127;
        float* plane = (c < 128) ? num_r : num_i;
        const int fs = s_flags[0], ls = s_flags[1];
        float num = 0.f, den = 0.f;
        int dprev = -1, rstart = 0;
        for (int r = 0; r < 64; ++r) {
            int d = s_dst[r];
            if (d != dprev) {
                if (dprev >= 0) {
                    if (rstart == 0 && fs) {
                        atomicAdd(&plane[(size_t)dprev * DIM + cc], num);
                        if (c == 0) atomicAdd(&denw[dprev], den);
                    } else {
                        plane[(size_t)dprev * DIM + cc] = tanhf(num / (den + 1e-10f));
                    }
                }
                dprev = d; num = 0.f; den = 0.f; rstart = r;
            }
            num += bf2f(u_sh[r * 260 + c]);
            den += exl[r];
        }
        if (dprev >= 0) {
            bool isb = (rstart == 0 && fs) || ls;
            if (isb) {
                atomicAdd(&plane[(size_t)dprev * DIM + cc], num);
                if (c == 0) atomicAdd(&denw[dprev], den);
            } else {
                plane[(size_t)dprev * DIM + cc] = tanhf(num / (den + 1e-10f));
            }
        }
    }
}

__global__ void boundary_finalize(const int* __restrict__ blist,
                                  const int* __restrict__ cnts,
                                  const float* __restrict__ denw,
                                  float* __restrict__ er,
                                  float* __restrict__ ei) {
    int j = blockIdx.x;
    if (j >= cnts[0]) return;
    int v = blist[j];
    int c = threadIdx.x;                 // 256
    float den = denw[v] + 1e-10f;
    float* plane = (c < 128) ? er : ei;
    size_t idx = (size_t)v * DIM + (c & 127);
    plane[idx] = tanhf(plane[idx] / den);
}

__global__ void gather_kernel(const int* __restrict__ sub,
                              const int* __restrict__ rel,
                              const float* __restrict__ relor,
                              const float* __restrict__ reloi,
                              float* __restrict__ out) {
    int idx = blockIdx.x * 256 + threadIdx.x;
    if (idx >= 4 * BATCH_Q * 32) return;
    int arr = idx >> 17;
    int rem = idx & 131071;
    int b = rem >> 5, c = rem & 31;
    const float* srcp;
    float* dstp;
    if (arr == 0)      { srcp = out + OUT_ER + (size_t)sub[b] * DIM; dstp = out + OUT_SUBR; }
    else if (arr == 1) { srcp = out + OUT_EI + (size_t)sub[b] * DIM; dstp = out + OUT_SUBI; }
    else if (arr == 2) { srcp = relor + (size_t)rel[b] * DIM;        dstp = out + OUT_RELR; }
    else               { srcp = reloi + (size_t)rel[b] * DIM;        dstp = out + OUT_RELI; }
    reinterpret_cast<float4*>(dstp + (size_t)b * DIM)[c] =
        reinterpret_cast<const float4*>(srcp)[c];
}

extern "C" void kernel_launch(void* const* d_in, const int* in_sizes, int n_in,
                              void* d_out, int out_size, void* d_ws, size_t ws_size,
                              hipStream_t stream) {
    const int*   eidx    = (const int*)d_in[0];
    const int*   etype   = (const int*)d_in[1];
    const int*   sub     = (const int*)d_in[2];
    const int*   rel     = (const int*)d_in[3];
    const float* emb_r   = (const float*)d_in[4];
    const float* emb_i   = (const float*)d_in[5];
    const float* relreal = (const float*)d_in[6];
    const float* relimag = (const float*)d_in[7];
    const float* im_proj = (const float*)d_in[8];
    const float* w_real  = (const float*)d_in[9];
    const float* w_imag  = (const float*)d_in[10];
    const float* w_rel   = (const float*)d_in[11];
    const float* att_a   = (const float*)d_in[12];

    float* out = (float*)d_out;
    float* ws  = (float*)d_ws;

    unsigned short* ent_ib = reinterpret_cast<unsigned short*>(ws + WS_ENTIB);
    unsigned short* ent_rb = reinterpret_cast<unsigned short*>(ws + WS_ENTRB);
    unsigned short* rel_rb = reinterpret_cast<unsigned short*>(ws + WS_RELRB);
    unsigned short* rel_ib = reinterpret_cast<unsigned short*>(ws + WS_RELIB);
    float* relor  = ws + WS_RELOR;
    float* reloi  = ws + WS_RELOI;
    float* denw   = ws + WS_DENOM;
    unsigned short* wb  = reinterpret_cast<unsigned short*>(ws + WS_BF16);
    unsigned short* Pb  = wb;
    unsigned short* Wtr = wb + 16384;
    unsigned short* Wti = wb + 32768;

    int* outi  = (int*)d_out;
    int* sp    = outi + SC_SP;
    int* sd    = outi + SC_SD;
    int* eo    = outi + SC_EO;
    int* blist = outi + SC_BLIST;
    int* zlist = outi + SC_ZLIST;
    int* cnts  = outi + SC_CNT;
    int* bsums = outi + SC_BSUM;

    hipMemsetAsync(denw, 0, (size_t)N_ENT * sizeof(float), stream);
    hipMemsetAsync(eo,   0, (size_t)N_ENT * sizeof(int), stream);
    hipMemsetAsync(cnts, 0, 64 * sizeof(int), stream);

    convert_w<<<192, 256, 0, stream>>>(im_proj, w_real, w_imag, wb);
    convert_entr<<<6250, 256, 0, stream>>>(emb_r, ent_rb);
    hist_kernel<<<(N_EDGE + 255) / 256, 256, 0, stream>>>(eidx, eo);
    scan1_kernel<<<98, 1024, 0, stream>>>(eo, bsums);
    scan2_kernel<<<1, 128, 0, stream>>>(bsums);
    scan3_kernel<<<98, 1024, 0, stream>>>(eo, bsums);
    classify_pre<<<(N_ENT + 255) / 256, 256, 0, stream>>>(eo, blist, zlist, cnts);
    zero_rows<<<16384, 256, 0, stream>>>(zlist, cnts, out + OUT_ER, out + OUT_EI);
    scatter_kernel<<<(N_EDGE + 255) / 256, 256, 0, stream>>>(eidx, etype, eo, sp, sd);
    proj_ent<<<1563, 512, 0, stream>>>(emb_i, Pb, ent_ib);
    rel_kernel<<<474, 128, 0, stream>>>(relreal, relimag, im_proj, w_rel,
                                        rel_rb, rel_ib, relor, reloi);
    edge_kernel<<<7813, 512, 0, stream>>>(sp, sd, ent_rb, ent_ib,
                                          rel_rb, rel_ib, Wtr, Wti, att_a,
                                          out + OUT_ER, out + OUT_EI, denw);
    boundary_finalize<<<8192, 256, 0, stream>>>(blist, cnts, denw,
                                                out + OUT_ER, out + OUT_EI);
    gather_kernel<<<2048, 256, 0, stream>>>(sub, rel, relor, reloi, out);
}